// Round 5
// baseline (1819.736 us; speedup 1.0000x reference)
//
#include <hip/hip_runtime.h>

// ---------------------------------------------------------------------------
// 3-kernel pipeline, full-B (no quarters, no c2 round-trip):
//  prep_weights: fp32->bf16 + K-permute; w_stem extended with w_vproj (K=1056)
//  convfused : conv1+conv2+conv3 in one kernel. 64 samp/wg, h-split: wg
//              computes conv2 fully (duplicated across h) + conv3 N-half.
//              W2 in LDS; Bf3[18]=72 VGPR; kq tables are compile consts.
//              c3out bf16 [B][1024] PRE-SWIZZLED (key srow&15) for stem_gru.
//  stem_gru  : stem GEMM (M=64,K=1056, single-buf A + reg prefetch) + GRU + fc.
//              LDS 48 KB -> 3 wgs/CU (R3 was 57 KB -> 2).
// R4 lesson: few fat wgs with resident weights beat many small wgs.
// ---------------------------------------------------------------------------

typedef short bf8 __attribute__((ext_vector_type(8)));   // 8 x bf16
typedef float f4  __attribute__((ext_vector_type(4)));   // MFMA C/D

#define MFMA(a, b, c) __builtin_amdgcn_mfma_f32_16x16x32_bf16(a, b, c, 0, 0, 0)

#define W3_OFF    18432
#define WSTEM_OFF 92160          // [192][1056]
#define WIH_OFF   294912         // [576][192]
#define WHH_OFF   405504
#define W_TOTAL   516096
#define C3_OFF    (1 << 20)      // shorts; c3out [65536][1024]

__device__ __forceinline__ unsigned short f2bf(float f) {
    unsigned int u = __float_as_uint(f);
    u += 0x7fffu + ((u >> 16) & 1u);          // RNE
    return (unsigned short)(u >> 16);
}
__device__ __forceinline__ float lrelu(float v) { return v > 0.f ? v : 0.05f * v; }
__device__ __forceinline__ float sigm(float x) { return 1.f / (1.f + __expf(-x)); }
__device__ __forceinline__ float tanh_(float x) {
    float e = __expf(2.f * x);
    return 1.f - 2.f / (e + 1.f);
}
__device__ __forceinline__ int swzC(int q, int s) {
    return q ^ ((s & 3) << 3) ^ ((q >> 1) & 32);
}

// ---- weight prep ----------------------------------------------------------
__global__ void prep_weights(const float* __restrict__ w2, const float* __restrict__ w3,
                             const float* __restrict__ wstem, const float* __restrict__ wvp,
                             const float* __restrict__ wih, const float* __restrict__ whh,
                             unsigned short* __restrict__ o) {
    int i = blockIdx.x * 256 + threadIdx.x;
    if (i >= W_TOTAL) return;
    float val;
    if (i < W3_OFF) {
        int n = i / 288, k = i - n * 288;
        val = w2[n * 288 + (k & 31) * 9 + (k >> 5)];
    } else if (i < WSTEM_OFF) {
        int d = i - W3_OFF;
        int n = d / 576, k = d - n * 576;
        val = w3[n * 576 + (k & 63) * 9 + (k >> 6)];
    } else if (i < WIH_OFF) {
        int d = i - WSTEM_OFF;
        int n = d / 1056, k = d - n * 1056;
        if (k < 1024)       val = wstem[(n << 10) + (k & 127) * 8 + (k >> 7)];
        else if (k < 1033)  val = wvp[n * 9 + (k - 1024)];
        else                val = 0.f;
    } else if (i < WHH_OFF) {
        val = wih[i - WIH_OFF];
    } else {
        val = whh[i - WHH_OFF];
    }
    o[i] = f2bf(val);
}

// ---- K1: fused conv1+conv2+conv3 ------------------------------------------
// 2048 wgs: sblk = bid>>1 (64 samples), h = bid&1 (conv3 N-half).
// LDS shorts: C1 [0,6144) | C2 [6144,12288) | W2 [12288,31232) stride 296.
__global__ __launch_bounds__(256, 2) void convfused(
    const float* __restrict__ x, const float* __restrict__ w1,
    const unsigned short* __restrict__ ws, unsigned short* __restrict__ c3)
{
    __shared__ __align__(16) unsigned short lds[31232];
    const int tid = threadIdx.x;
    const int wave = tid >> 6, lane = tid & 63;
    const int col = lane & 15, quad = lane >> 4;
    const int h = blockIdx.x & 1;
    const int S0 = (blockIdx.x >> 1) * 64;
    const int q8 = quad * 8;

    // stage W2 ([64][288] -> LDS stride 296 to break banks)
    {
        int row = tid >> 2, seg = tid & 3;
        const unsigned short* src = ws + row * 288 + seg * 72;
        unsigned short* dst = &lds[12288 + row * 296 + seg * 72];
        #pragma unroll
        for (int i = 0; i < 9; ++i)
            *(bf8*)(dst + i * 8) = *(const bf8*)(src + i * 8);
    }

    // Bf3: one 16-ch n-tile per wave within this wg's half
    const int n_in = h * 64 + wave * 16 + col;
    bf8 Bf3[18];
    #pragma unroll
    for (int ks = 0; ks < 18; ++ks)
        Bf3[ks] = *(const bf8*)(ws + W3_OFF + n_in * 576 + ks * 32 + q8);

    // conv2 loop-invariant addressing
    const int scm = col & 3;                      // m&3 for all conv2 A m-tiles
    const int bb2 = scm * 1536, sw2 = scm << 3;
    int qbv[6];
    #pragma unroll
    for (int mt = 0; mt < 3; ++mt)
        #pragma unroll
        for (int hf = 0; hf < 2; ++hf) {
            int p = mt * 8 + hf * 4 + (col >> 2);
            int oy = p / 6, ox = p - 6 * oy;
            qbv[mt * 2 + hf] = (oy * 8 + ox) * 32;
        }
    // conv3 loop-invariant addressing
    const int s3 = col & 3;
    const int p30 = col >> 2, p31 = p30 + 4;
    const int qb30 = p30 * 64;                    // (0*6 + p30)*64, p30<4
    const int qb31 = (6 + (p31 & 3)) * 64;
    const int b3 = 6144 + s3 * 1536;
    const int G = h * 8 + wave * 2 + (col >> 3);

    __syncthreads();

    for (int c = 0; c < 16; ++c) {
        // ---- conv1: 2x2 s2, 1->32ch -> C1 [s][p48][co32] swizzled
        if (tid < 192) {
            int s = tid / 48, p = tid - s * 48;
            int y = p >> 3, xx = p & 7;
            const float* xp = x + (size_t)(S0 + c * 4 + s) * 192 + y * 32 + xx * 2;
            float x00 = xp[0], x01 = xp[1], x10 = xp[16], x11 = xp[17];
            int base = s * 1536, sw = (s & 3) << 3;
            #pragma unroll
            for (int cc = 0; cc < 32; ++cc) {
                int co = (cc + p) & 31;
                float a = x00 * w1[co * 4] + x01 * w1[co * 4 + 1]
                        + x10 * w1[co * 4 + 2] + x11 * w1[co * 4 + 3];
                lds[base + ((p * 32 + co) ^ sw)] = f2bf(lrelu(a));
            }
        }
        __syncthreads();

        // ---- conv2: M=96, N=64 (wave n-tile), K=288; B from LDS, ks-outer
        {
            f4 a2[6];
            #pragma unroll
            for (int i = 0; i < 6; ++i) a2[i] = (f4){0.f, 0.f, 0.f, 0.f};
            const int brow = 12288 + (wave * 16 + col) * 296;
            #pragma unroll
            for (int ks = 0; ks < 9; ++ks) {
                bf8 b = *(const bf8*)&lds[brow + ks * 32 + q8];
                const int kqc = ((ks / 3) * 8 + (ks % 3)) * 32 + q8;
                #pragma unroll
                for (int i = 0; i < 6; ++i) {
                    bf8 a = *(const bf8*)&lds[bb2 + ((qbv[i] + kqc) ^ sw2)];
                    a2[i] = MFMA(a, b, a2[i]);
                }
            }
            // epilogue -> C2 [s][pos24][ci64] swizzled
            #pragma unroll
            for (int mt = 0; mt < 3; ++mt)
                #pragma unroll
                for (int hf = 0; hf < 2; ++hf) {
                    f4 ac = a2[mt * 2 + hf];
                    #pragma unroll
                    for (int r = 0; r < 4; ++r) {
                        int m = mt * 32 + hf * 16 + quad * 4 + r;
                        int s = m & 3, pos = m >> 2;
                        int q = pos * 64 + wave * 16 + col;
                        lds[6144 + s * 1536 + swzC(q, s)] = f2bf(lrelu(ac[r]));
                    }
                }
        }
        __syncthreads();

        // ---- conv3: M=32, N=16/wave, K=576 -> global (pre-swizzled)
        {
            f4 a30 = {0.f, 0.f, 0.f, 0.f}, a31 = {0.f, 0.f, 0.f, 0.f};
            #pragma unroll
            for (int ks = 0; ks < 18; ++ks) {
                const int kqc = ((ks / 6) * 6 + ((ks % 6) >> 1)) * 64
                              + ((ks % 6) & 1) * 32 + q8;
                bf8 x0 = *(const bf8*)&lds[b3 + swzC(qb30 + kqc, s3)];
                bf8 x1 = *(const bf8*)&lds[b3 + swzC(qb31 + kqc, s3)];
                a30 = MFMA(x0, Bf3[ks], a30);
                a31 = MFMA(x1, Bf3[ks], a31);
            }
            #pragma unroll
            for (int r = 0; r < 4; ++r) {
                int srow = S0 + c * 4 + r;                  // s = r for both halves
                int key = (G ^ (srow & 15)) << 3;
                c3[(size_t)srow * 1024 + quad * 128 + key + (col & 7)]
                    = f2bf(lrelu(a30[r]));
                c3[(size_t)srow * 1024 + (quad + 4) * 128 + key + (col & 7)]
                    = f2bf(lrelu(a31[r]));
            }
        }
        __syncthreads();
    }
}

// ---- K2: stem GEMM + GRU + fc --------------------------------------------
// 1024 wgs, M=64 samples/wg. LDS shorts: FUSED [0,12288) key m&7 |
// shared [12288,24576): A-buf (single, 8192) then HX [64][192] key m&7.
__global__ __launch_bounds__(256, 3) void stem_gru(
    const unsigned short* __restrict__ ws, const float* __restrict__ v,
    const float* __restrict__ hx, const float* __restrict__ bvp,
    const float* __restrict__ bih, const float* __restrict__ bhh,
    const float* __restrict__ wfc, float* __restrict__ out)
{
    __shared__ __align__(16) unsigned short lds[24576];
    const int tid = threadIdx.x;
    const int wave = tid >> 6, lane = tid & 63;
    const int col = lane & 15, quad = lane >> 4;
    const int S0 = blockIdx.x * 64;
    const unsigned short* c3 = ws + C3_OFF;
    const unsigned short* wstem = ws + WSTEM_OFF;

    // ============ phase A: stem GEMM, K=1056 (v_proj fused as K-tail) ======
    f4 acc[4][3];
    #pragma unroll
    for (int mt = 0; mt < 4; ++mt)
        #pragma unroll
        for (int t = 0; t < 3; ++t) acc[mt][t] = (f4){0.f, 0.f, 0.f, 0.f};

    const int sm = tid >> 2, sq = tid & 3;
    const unsigned short* asrc = c3 + (size_t)(S0 + sm) * 1024 + sq * 32;

    #pragma unroll
    for (int i = 0; i < 4; ++i)
        *(bf8*)&lds[12288 + sm * 128 + sq * 32 + i * 8] = *(const bf8*)(asrc + i * 8);
    __syncthreads();

    for (int kc = 0; kc < 8; ++kc) {
        bf8 nx[4];
        if (kc < 7) {
            const unsigned short* s2 = asrc + (kc + 1) * 128;
            #pragma unroll
            for (int i = 0; i < 4; ++i) nx[i] = *(const bf8*)(s2 + i * 8);
        }
        #pragma unroll
        for (int ks = 0; ks < 4; ++ks) {
            int kl = ks * 32 + quad * 8;
            int kk = kc * 128 + kl;
            bf8 b0 = *(const bf8*)(wstem + (wave * 48 + col) * 1056 + kk);
            bf8 b1 = *(const bf8*)(wstem + (wave * 48 + 16 + col) * 1056 + kk);
            bf8 b2 = *(const bf8*)(wstem + (wave * 48 + 32 + col) * 1056 + kk);
            #pragma unroll
            for (int mt = 0; mt < 4; ++mt) {
                int m = mt * 16 + col;
                bf8 a = *(const bf8*)&lds[12288 + m * 128 + (kl ^ ((m & 15) << 3))];
                acc[mt][0] = MFMA(a, b0, acc[mt][0]);
                acc[mt][1] = MFMA(a, b1, acc[mt][1]);
                acc[mt][2] = MFMA(a, b2, acc[mt][2]);
            }
        }
        __syncthreads();                        // all reads of A-buf done
        if (kc < 7) {
            #pragma unroll
            for (int i = 0; i < 4; ++i)
                *(bf8*)&lds[12288 + sm * 128 + sq * 32 + i * 8] = nx[i];
        }
        __syncthreads();                        // writes visible
    }

    // K-tail: v (9 cols, zero-padded to 32) into A-buf
    if (tid < 64) {
        int m = tid;
        const float* vp = v + (size_t)(S0 + m) * 9;
        __align__(16) unsigned short tmp[32];
        #pragma unroll
        for (int i = 0; i < 9; ++i) tmp[i] = f2bf(vp[i]);
        #pragma unroll
        for (int i = 9; i < 32; ++i) tmp[i] = 0;
        #pragma unroll
        for (int gg = 0; gg < 4; ++gg) {
            int gp = gg ^ (m & 15);
            *(bf8*)&lds[12288 + m * 128 + gp * 8] = *(bf8*)&tmp[gg * 8];
        }
    }
    __syncthreads();
    {
        int kl = quad * 8;
        bf8 b0 = *(const bf8*)(wstem + (wave * 48 + col) * 1056 + 1024 + kl);
        bf8 b1 = *(const bf8*)(wstem + (wave * 48 + 16 + col) * 1056 + 1024 + kl);
        bf8 b2 = *(const bf8*)(wstem + (wave * 48 + 32 + col) * 1056 + 1024 + kl);
        #pragma unroll
        for (int mt = 0; mt < 4; ++mt) {
            int m = mt * 16 + col;
            bf8 a = *(const bf8*)&lds[12288 + m * 128 + (kl ^ ((m & 15) << 3))];
            acc[mt][0] = MFMA(a, b0, acc[mt][0]);
            acc[mt][1] = MFMA(a, b1, acc[mt][1]);
            acc[mt][2] = MFMA(a, b2, acc[mt][2]);
        }
    }
    __syncthreads();   // A-buf reads done before HX overwrite below

    // epilogue: + bias, lrelu -> FUSED [0,12288)
    #pragma unroll
    for (int t = 0; t < 3; ++t) {
        int n = wave * 48 + t * 16 + col;
        float bb = bvp[n];
        #pragma unroll
        for (int mt = 0; mt < 4; ++mt)
            #pragma unroll
            for (int r = 0; r < 4; ++r) {
                int m = mt * 16 + quad * 4 + r;
                lds[m * 192 + (n ^ ((m & 7) << 3))] = f2bf(lrelu(acc[mt][t][r] + bb));
            }
    }

    // ============ phase B: GRU ============================================
    // stage hx bf16 -> [12288,24576)  [64][192] key m&7
    {
        int m = tid >> 2, qq = tid & 3;
        const float* hp = hx + (size_t)(S0 + m) * 192 + qq * 48;
        #pragma unroll
        for (int i = 0; i < 6; ++i) {
            f4 d  = *(const f4*)(hp + i * 8 + 0);
            f4 d2 = *(const f4*)(hp + i * 8 + 4);
            __align__(16) unsigned short tmp[8];
            #pragma unroll
            for (int u = 0; u < 4; ++u) { tmp[u] = f2bf(d[u]); tmp[4 + u] = f2bf(d2[u]); }
            int gg = qq * 6 + i, gp = gg ^ (m & 7);
            *(bf8*)&lds[12288 + m * 192 + gp * 8] = *(bf8*)tmp;
        }
    }
    __syncthreads();

    #pragma unroll
    for (int t = 0; t < 3; ++t) {
        int j0 = (wave * 3 + t) * 16;
        int j = j0 + col;
        const unsigned short* pih = ws + WIH_OFF + j * 192;
        const unsigned short* phh = ws + WHH_OFF + j * 192;
        f4 g0[4], g1[4], g2[4], g3[4], g4[4], g5[4];
        #pragma unroll
        for (int mt = 0; mt < 4; ++mt) {
            g0[mt] = (f4){0.f,0.f,0.f,0.f}; g1[mt] = g0[mt]; g2[mt] = g0[mt];
            g3[mt] = g0[mt]; g4[mt] = g0[mt]; g5[mt] = g0[mt];
        }
        #pragma unroll
        for (int ks = 0; ks < 6; ++ks) {
            int k0 = ks * 32 + quad * 8;
            bf8 bir = *(const bf8*)(pih + k0);
            bf8 bhr = *(const bf8*)(phh + k0);
            bf8 biz = *(const bf8*)(pih + 36864 + k0);
            bf8 bhz = *(const bf8*)(phh + 36864 + k0);
            bf8 bin = *(const bf8*)(pih + 73728 + k0);
            bf8 bhn = *(const bf8*)(phh + 73728 + k0);
            #pragma unroll
            for (int mt = 0; mt < 4; ++mt) {
                int m = mt * 16 + col;
                int off = m * 192 + (k0 ^ ((m & 7) << 3));
                bf8 aF = *(const bf8*)&lds[off];
                bf8 aH = *(const bf8*)&lds[12288 + off];
                g0[mt] = MFMA(aF, bir, g0[mt]);
                g1[mt] = MFMA(aH, bhr, g1[mt]);
                g2[mt] = MFMA(aF, biz, g2[mt]);
                g3[mt] = MFMA(aH, bhz, g3[mt]);
                g4[mt] = MFMA(aF, bin, g4[mt]);
                g5[mt] = MFMA(aH, bhn, g5[mt]);
            }
        }
        float b_ir = bih[j], b_iz = bih[192 + j], b_in = bih[384 + j];
        float b_hr = bhh[j], b_hz = bhh[192 + j], b_hn = bhh[384 + j];
        #pragma unroll
        for (int mt = 0; mt < 4; ++mt)
            #pragma unroll
            for (int r = 0; r < 4; ++r) {
                int s = mt * 16 + quad * 4 + r;
                float rg = sigm(g0[mt][r] + b_ir + g1[mt][r] + b_hr);
                float zg = sigm(g2[mt][r] + b_iz + g3[mt][r] + b_hz);
                float ng = tanh_(g4[mt][r] + b_in + rg * (g5[mt][r] + b_hn));
                float hxv = hx[(size_t)(S0 + s) * 192 + j];
                float hnew = (1.f - zg) * ng + zg * hxv;
                out[262144 + (size_t)(S0 + s) * 192 + j] = hnew;
            }
    }
    __syncthreads();   // drain hnew stores

    // fc head: thread (s = tid&63, a = tid>>6), re-reads hnew from out (L2-hot)
    {
        int s = tid & 63, a = tid >> 6;
        const float* hp = out + 262144 + (size_t)(S0 + s) * 192;
        const float* wf = wfc + a * 192;
        float sum = 0.f;
        #pragma unroll 4
        for (int jj = 0; jj < 48; ++jj) {
            f4 hv = *(const f4*)(hp + jj * 4);
            f4 wv = *(const f4*)(wf + jj * 4);
            #pragma unroll
            for (int u = 0; u < 4; ++u) sum += lrelu(hv[u]) * wv[u];
        }
        out[(size_t)(S0 + s) * 4 + a] = sum;
    }
}

// ---------------------------------------------------------------------------
extern "C" void kernel_launch(void* const* d_in, const int* in_sizes, int n_in,
                              void* d_out, int out_size, void* d_ws, size_t ws_size,
                              hipStream_t stream) {
    const float* x     = (const float*)d_in[0];
    const float* v     = (const float*)d_in[1];
    const float* hx    = (const float*)d_in[2];
    const float* w1    = (const float*)d_in[3];
    const float* w2    = (const float*)d_in[4];
    const float* w3    = (const float*)d_in[5];
    const float* wstem = (const float*)d_in[6];
    const float* wvp   = (const float*)d_in[7];
    const float* bvp   = (const float*)d_in[8];
    const float* wih   = (const float*)d_in[9];
    const float* whh   = (const float*)d_in[10];
    const float* bih   = (const float*)d_in[11];
    const float* bhh   = (const float*)d_in[12];
    const float* wfc   = (const float*)d_in[13];
    unsigned short* wsp = (unsigned short*)d_ws;

    prep_weights<<<2016, 256, 0, stream>>>(w2, w3, wstem, wvp, wih, whh, wsp);
    convfused<<<2048, 256, 0, stream>>>(x, w1, wsp, wsp + C3_OFF);
    stem_gru<<<1024, 256, 0, stream>>>(wsp, v, hx, bvp, bih, bhh, wfc, (float*)d_out);
}